// Round 1
// 749.000 us; speedup vs baseline: 1.3339x; 1.3339x over previous
//
#include <hip/hip_runtime.h>
#include <hip/hip_bf16.h>
#include <stdint.h>

// ---------------------------------------------------------------------------
// Pipeline:
//  K0 f32_to_bf16:    ws.Wnet_bf = bf16(W_net)                 [25088,1568]
//  K1 gemm_nt_lp:     ws.x_bf[:, :784] = bf16((xd@W_lp^T + b_lp - .5)/.2)
//  K2 build_restored: ws.x_bf[:, 784:] = bf16((x_restored - .5)/.2)
//  K3 gemm_mfma_bf16: d_out = (x_bf @ Wnet_bf^T + b_net)*0.2   [2048,25088] f32
//  K4 gs_cholesky:    Gram-Schmidt via per-batch Cholesky:
//                     G = W W^T (MFMA), L = chol(G), M = diag(L) L^-1,
//                     out_i = w_i + sum_{j<i} M_ij w_j  (== CGS output)
// ---------------------------------------------------------------------------

typedef short s16x8 __attribute__((ext_vector_type(8)));
typedef float f32x4 __attribute__((ext_vector_type(4)));

#define GL_LDS16(gptr, lptr)                                                   \
    __builtin_amdgcn_global_load_lds(                                          \
        (const __attribute__((address_space(1))) void*)(gptr),                 \
        (__attribute__((address_space(3))) void*)(lptr), 16, 0, 0)

// ============================ K3: MFMA GEMM ================================
// C[m][n] = (sum_k A[m][k]*B[n][k] + bias[n]) * 0.2
// A: [M][K] bf16 row-major, B: [N][K] bf16 row-major. M%128==0, N%128==0,
// K%32==0. 128x128 tile, BK=32, 4 waves in 2x2, 16x16x32 MFMA, 4x4 frags.
__global__ __launch_bounds__(256) void gemm_mfma_bf16(
    const __hip_bfloat16* __restrict__ A, const __hip_bfloat16* __restrict__ B,
    const float* __restrict__ bias, float* __restrict__ C,
    int M, int N, int K)
{
    __shared__ short ldsA[4096];  // 8 KB
    __shared__ short ldsB[4096];  // 8 KB

    const int t = threadIdx.x;
    const int l = t & 63;
    const int w = t >> 6;          // wave 0..3
    const int wr = w >> 1;         // wave row 0..1 (64-row half)
    const int wc = w & 1;          // wave col 0..1 (64-col half)
    const int m0 = blockIdx.y * 128;
    const int n0 = blockIdx.x * 128;

    const short* As = (const short*)A;
    const short* Bs = (const short*)B;

    const int g0 = w, rb0 = 0;
    const int g1 = w, rb1 = 64;

    const size_t arow0 = (size_t)(m0 + rb0 + l) * K;
    const size_t arow1 = (size_t)(m0 + rb1 + l) * K;
    const size_t brow0 = (size_t)(n0 + rb0 + l) * K;
    const size_t brow1 = (size_t)(n0 + rb1 + l) * K;
    const int lbase0 = g0 * 1024 + rb0 * 8;
    const int lbase1 = g1 * 1024 + rb1 * 8;

    const int fb = (l >> 4) * 1024 + (l & 15) * 8;
    const int fbA = fb + wr * 64 * 8;
    const int fbB = fb + wc * 64 * 8;

    f32x4 acc[4][4] = {};

    for (int k0 = 0; k0 < K; k0 += 32) {
        GL_LDS16(As + arow0 + k0 + g0 * 8, &ldsA[lbase0]);
        GL_LDS16(As + arow1 + k0 + g1 * 8, &ldsA[lbase1]);
        GL_LDS16(Bs + brow0 + k0 + g0 * 8, &ldsB[lbase0]);
        GL_LDS16(Bs + brow1 + k0 + g1 * 8, &ldsB[lbase1]);
        __syncthreads();

        s16x8 af[4], bf[4];
        #pragma unroll
        for (int mi = 0; mi < 4; ++mi)
            af[mi] = *(const s16x8*)&ldsA[fbA + mi * 16 * 8];
        #pragma unroll
        for (int ni = 0; ni < 4; ++ni)
            bf[ni] = *(const s16x8*)&ldsB[fbB + ni * 16 * 8];

        #pragma unroll
        for (int mi = 0; mi < 4; ++mi)
            #pragma unroll
            for (int ni = 0; ni < 4; ++ni)
                acc[mi][ni] = __builtin_amdgcn_mfma_f32_16x16x32_bf16(
                    af[mi], bf[ni], acc[mi][ni], 0, 0, 0);

        __syncthreads();
    }

    const int row0 = m0 + wr * 64 + (l >> 4) * 4;
    const int col0 = n0 + wc * 64 + (l & 15);
    #pragma unroll
    for (int ni = 0; ni < 4; ++ni) {
        const int n = col0 + ni * 16;
        const float bn = bias[n];
        #pragma unroll
        for (int mi = 0; mi < 4; ++mi) {
            const int r0 = row0 + mi * 16;
            #pragma unroll
            for (int r = 0; r < 4; ++r)
                C[(size_t)(r0 + r) * N + n] = (acc[mi][ni][r] + bn) * 0.2f;
        }
    }
}

// ============================ K0: f32 -> bf16 ==============================
__global__ __launch_bounds__(256) void f32_to_bf16(
    const float* __restrict__ in, __hip_bfloat16* __restrict__ out, int n4)
{
    int i = blockIdx.x * blockDim.x + threadIdx.x;
    const int stride = gridDim.x * blockDim.x;
    for (; i < n4; i += stride) {
        float4 v = ((const float4*)in)[i];
        __hip_bfloat16 o[4] = {
            __float2bfloat16(v.x), __float2bfloat16(v.y),
            __float2bfloat16(v.z), __float2bfloat16(v.w)};
        *(ushort4*)&out[(size_t)i * 4] = *(const ushort4*)o;
    }
}

// ===================== K1: small fp32 GEMM (NT) ============================
#define TILE_M 64
#define TILE_N 64
#define TILE_K 16
#define LDS_STRIDE 72

__global__ __launch_bounds__(256) void gemm_nt_lp(
    const float* __restrict__ A, const float* __restrict__ B,
    const float* __restrict__ bias, __hip_bfloat16* __restrict__ C,
    int M, int N, int K, int ldc)
{
    __shared__ float As[TILE_K][LDS_STRIDE];
    __shared__ float Bsh[TILE_K][LDS_STRIDE];

    const int t  = threadIdx.x;
    const int tx = t & 15;
    const int ty = t >> 4;
    const int m0 = blockIdx.y * TILE_M;
    const int n0 = blockIdx.x * TILE_N;
    const int lrow = t >> 2;
    const int lk   = (t & 3) << 2;

    float acc[4][4] = {};

    for (int kt = 0; kt < K; kt += TILE_K) {
        float4 av = *(const float4*)(A + (size_t)(m0 + lrow) * K + kt + lk);
        float4 bv = make_float4(0.f, 0.f, 0.f, 0.f);
        if (n0 + lrow < N)
            bv = *(const float4*)(B + (size_t)(n0 + lrow) * K + kt + lk);

        __syncthreads();
        As[lk + 0][lrow] = av.x; As[lk + 1][lrow] = av.y;
        As[lk + 2][lrow] = av.z; As[lk + 3][lrow] = av.w;
        Bsh[lk + 0][lrow] = bv.x; Bsh[lk + 1][lrow] = bv.y;
        Bsh[lk + 2][lrow] = bv.z; Bsh[lk + 3][lrow] = bv.w;
        __syncthreads();

        #pragma unroll
        for (int k = 0; k < TILE_K; ++k) {
            float4 a = *(const float4*)&As[k][ty << 2];
            float4 b = *(const float4*)&Bsh[k][tx << 2];
            acc[0][0] += a.x * b.x; acc[0][1] += a.x * b.y;
            acc[0][2] += a.x * b.z; acc[0][3] += a.x * b.w;
            acc[1][0] += a.y * b.x; acc[1][1] += a.y * b.y;
            acc[1][2] += a.y * b.z; acc[1][3] += a.y * b.w;
            acc[2][0] += a.z * b.x; acc[2][1] += a.z * b.y;
            acc[2][2] += a.z * b.z; acc[2][3] += a.z * b.w;
            acc[3][0] += a.w * b.x; acc[3][1] += a.w * b.y;
            acc[3][2] += a.w * b.z; acc[3][3] += a.w * b.w;
        }
    }

    #pragma unroll
    for (int j = 0; j < 4; ++j) {
        int n = n0 + (tx << 2) + j;
        if (n < N) {
            float bn = bias[n];
            #pragma unroll
            for (int i = 0; i < 4; ++i) {
                float v = (acc[i][j] + bn - 0.5f) / 0.2f;
                C[(size_t)(m0 + (ty << 2) + i) * ldc + n] = __float2bfloat16(v);
            }
        }
    }
}

// ===================== K2: restored half, bf16 =============================
__global__ __launch_bounds__(256) void build_restored(
    const float* __restrict__ xr, __hip_bfloat16* __restrict__ x)
{
    const int b = blockIdx.x;
    const int t = threadIdx.x;
    if (t < 196) {
        float4 v = *(const float4*)(xr + (size_t)b * 784 + (t << 2));
        __hip_bfloat16 o[4] = {
            __float2bfloat16((v.x - 0.5f) / 0.2f),
            __float2bfloat16((v.y - 0.5f) / 0.2f),
            __float2bfloat16((v.z - 0.5f) / 0.2f),
            __float2bfloat16((v.w - 0.5f) / 0.2f)};
        *(ushort4*)&x[(size_t)b * 1568 + 784 + (t << 2)] = *(const ushort4*)o;
    }
}

// ================= K4: Gram-Schmidt via Cholesky ===========================
// Math: CGS output out = diag(L) * L^-1 * W where G = W W^T = L L^T.
// Per batch (block): stage W (32x784) as swizzled bf16 in LDS; 4 waves
// compute the 2x2 quadrants of G via 16x16x32 MFMA; lane-parallel Cholesky
// and triangular inversion in LDS (f32); apply out_i = w_i + sum_{j<i}
// M_ij * w_j with w_i read exact f32 from global, w_j bf16 from LDS.
#define GS_N  32
#define GS_D  784
#define GS_KP 832   // padded K: 26 * 32 (tail zero-filled)

__device__ __forceinline__ float b2f(unsigned short u) {
    union { unsigned i; float f; } c; c.i = ((unsigned)u) << 16; return c.f;
}

__global__ __launch_bounds__(256) void gs_cholesky(float* __restrict__ out)
{
    // XOR-swizzled: 16B granule g of row r stored at granule (g ^ (r&7)).
    // Makes both the MFMA fragment reads (16 lanes, 16 rows, same k) and the
    // broadcast apply reads <=2-way bank patterns.
    __shared__ __align__(16) short Whi[GS_N * GS_KP];  // 53248 B
    __shared__ float Gs[GS_N][GS_N + 1];               // 4224 B (G -> L)
    __shared__ float Ms[GS_N][GS_N + 1];               // 4224 B (T -> M)
    __shared__ float Ld[GS_N];                         // diag(L)

    const int t = threadIdx.x;
    const int l = t & 63;
    const int w = t >> 6;
    float* row0 = out + (size_t)blockIdx.x * (GS_N * GS_D);

    // ---- P0: stage W rows as bf16 into swizzled LDS (zero-fill pad) ----
    if (t < 208) {                        // 208 half-granules of 4 elems
        const int g   = t >> 1;           // 16B granule 0..103
        const int sub = (t & 1) << 2;     // elem offset within granule
        #pragma unroll 8
        for (int r = 0; r < GS_N; ++r) {
            ushort4 h = make_ushort4(0, 0, 0, 0);
            if (t < 196) {
                float4 v = *(const float4*)(row0 + r * GS_D + (t << 2));
                __hip_bfloat16 hb[4] = {
                    __float2bfloat16(v.x), __float2bfloat16(v.y),
                    __float2bfloat16(v.z), __float2bfloat16(v.w)};
                h = *(const ushort4*)hb;
            }
            const int gp = g ^ (r & 7);
            *(ushort4*)&Whi[r * GS_KP + (gp << 3) + sub] = h;
        }
    }
    __syncthreads();

    // ---- P1: Gram G = W W^T via MFMA; wave w -> 16x16 quadrant ----
    {
        const int wr = w >> 1, wc = w & 1;
        const int ra = wr * 16 + (l & 15);   // A row (M index)
        const int rb = wc * 16 + (l & 15);   // B row (N index)
        const int kg = l >> 4;               // k-subgroup 0..3
        f32x4 acc = {};
        #pragma unroll
        for (int s = 0; s < GS_KP / 32; ++s) {
            const int ga = ((s << 2) + kg) ^ (ra & 7);
            const int gb = ((s << 2) + kg) ^ (rb & 7);
            s16x8 af = *(const s16x8*)&Whi[ra * GS_KP + (ga << 3)];
            s16x8 bf = *(const s16x8*)&Whi[rb * GS_KP + (gb << 3)];
            acc = __builtin_amdgcn_mfma_f32_16x16x32_bf16(af, bf, acc, 0, 0, 0);
        }
        // C/D layout: col = lane&15, row = (lane>>4)*4 + reg
        const int di = wr * 16 + (l >> 4) * 4;
        const int dj = wc * 16 + (l & 15);
        #pragma unroll
        for (int r = 0; r < 4; ++r) Gs[di + r][dj] = acc[r];
    }
    __syncthreads();

    // ---- P2: Cholesky, lower triangle in place (diag kept in Ld) ----
    for (int k = 0; k < GS_N; ++k) {
        const float sk = sqrtf(Gs[k][k]);   // broadcast read, no writer
        if (t == k) Ld[k] = sk;
        if (t > k && t < GS_N) Gs[t][k] /= sk;
        __syncthreads();
        if (t > k && t < GS_N) {
            const float lik = Gs[t][k];
            for (int j = k + 1; j <= t; ++j)
                Gs[t][j] -= lik * Gs[j][k];
        }
        __syncthreads();
    }

    // ---- P3: M = diag(L) * L^-1, column-parallel forward substitution ----
    if (t < GS_N) {
        const int j = t;
        Ms[j][j] = 1.0f / Ld[j];            // T[j][j] (unused by apply)
        for (int i = j + 1; i < GS_N; ++i) {
            float a = 0.f;
            for (int k = j; k < i; ++k)
                a += Gs[i][k] * Ms[k][j];   // L[i][k] * T[k][j]
            Ms[i][j] = -a / Ld[i];          // T[i][j]
        }
        for (int i = j + 1; i < GS_N; ++i)
            Ms[i][j] *= Ld[i];              // M[i][j] = L_ii * T[i][j]
    }
    __syncthreads();

    // ---- P4: apply out_i = w_i + sum_{j<i} M_ij * w_j (barrier-free) ----
    if (t < 196) {
        const int gg = t >> 1;
        const int sb = (t & 1) << 2;
        float4 vcur = *(const float4*)(row0 + (t << 2));     // row 0
        for (int i = 0; i < GS_N; ++i) {
            float4 vnxt = vcur;
            if (i + 1 < GS_N)                                 // prefetch
                vnxt = *(const float4*)(row0 + (i + 1) * GS_D + (t << 2));
            float cx = 0.f, cy = 0.f, cz = 0.f, cw = 0.f;
            #pragma unroll 4
            for (int j = 0; j < i; ++j) {
                const float m = Ms[i][j];
                const ushort4 h = *(const ushort4*)
                    &Whi[j * GS_KP + (((gg ^ (j & 7))) << 3) + sb];
                cx += m * b2f(h.x); cy += m * b2f(h.y);
                cz += m * b2f(h.z); cw += m * b2f(h.w);
            }
            vcur.x += cx; vcur.y += cy; vcur.z += cz; vcur.w += cw;
            *(float4*)(row0 + i * GS_D + (t << 2)) = vcur;
            vcur = vnxt;
        }
    }
}

// ================================ launch ===================================
extern "C" void kernel_launch(void* const* d_in, const int* in_sizes, int n_in,
                              void* d_out, int out_size, void* d_ws, size_t ws_size,
                              hipStream_t stream)
{
    const float* xd   = (const float*)d_in[0];  // [2048, 832]
    const float* xr   = (const float*)d_in[1];  // [2048, 1, 28, 28]
    const float* Wlp  = (const float*)d_in[2];  // [784, 832]
    const float* blp  = (const float*)d_in[3];  // [784]
    const float* Wnet = (const float*)d_in[4];  // [25088, 1568]
    const float* bnet = (const float*)d_in[5];  // [25088]
    float* out = (float*)d_out;                 // [2048, 32, 784] f32

    const int B = 2048, IN_LP = 832, IMG = 784, IN_NET = 1568, OUT = 32 * 784;

    __hip_bfloat16* Wnet_bf = (__hip_bfloat16*)d_ws;
    __hip_bfloat16* x_bf =
        (__hip_bfloat16*)((char*)d_ws + (size_t)OUT * IN_NET * 2);

    // K0: W_net fp32 -> bf16
    f32_to_bf16<<<2048, 256, 0, stream>>>(Wnet, Wnet_bf, OUT * IN_NET / 4);

    // K1: linear projection + normalize -> bf16 x[:, :784]
    gemm_nt_lp<<<dim3((IMG + TILE_N - 1) / TILE_N, B / TILE_M), 256, 0, stream>>>(
        xd, Wlp, blp, x_bf, B, IMG, IN_LP, IN_NET);

    // K2: normalized restored image -> bf16 x[:, 784:]
    build_restored<<<B, 256, 0, stream>>>(xr, x_bf);

    // K3: big MFMA GEMM -> d_out (fp32)
    gemm_mfma_bf16<<<dim3(OUT / 128, B / 128), 256, 0, stream>>>(
        x_bf, Wnet_bf, bnet, out, B, OUT, IN_NET);

    // K4: Gram-Schmidt via per-batch Cholesky, in place on d_out
    gs_cholesky<<<B, 256, 0, stream>>>(out);
}

// Round 2
// 579.648 us; speedup vs baseline: 1.7236x; 1.2922x over previous
//
#include <hip/hip_runtime.h>
#include <hip/hip_bf16.h>
#include <stdint.h>

// ---------------------------------------------------------------------------
// Pipeline:
//  K0 f32_to_bf16:    ws.Wnet_bf = bf16(W_net)                 [25088,1568]
//  K1 gemm_nt_lp:     ws.x_bf[:, :784] = bf16((xd@W_lp^T + b_lp - .5)/.2)
//  K2 build_restored: ws.x_bf[:, 784:] = bf16((x_restored - .5)/.2)
//  K3 gemm_mfma_bf16: d_out = (x_bf @ Wnet_bf^T + b_net)*0.2   [2048,25088] f32
//  K4a gram_solve:    per batch: G = W W^T (chunked MFMA), L = chol(G),
//                     M = diag(L) L^-1  -> ws (reuses Wnet_bf region)
//  K4b gs_apply:      out_i = w_i + sum_{j<i} M_ij w_j  (chunked, f32)
// ---------------------------------------------------------------------------

typedef short s16x8 __attribute__((ext_vector_type(8)));
typedef float f32x4 __attribute__((ext_vector_type(4)));

#define GL_LDS16(gptr, lptr)                                                   \
    __builtin_amdgcn_global_load_lds(                                          \
        (const __attribute__((address_space(1))) void*)(gptr),                 \
        (__attribute__((address_space(3))) void*)(lptr), 16, 0, 0)

// ============================ K3: MFMA GEMM ================================
// C[m][n] = (sum_k A[m][k]*B[n][k] + bias[n]) * 0.2
// A: [M][K] bf16 row-major, B: [N][K] bf16 row-major. M%128==0, N%128==0,
// K%32==0. 128x128 tile, BK=32, 4 waves in 2x2, 16x16x32 MFMA, 4x4 frags.
__global__ __launch_bounds__(256) void gemm_mfma_bf16(
    const __hip_bfloat16* __restrict__ A, const __hip_bfloat16* __restrict__ B,
    const float* __restrict__ bias, float* __restrict__ C,
    int M, int N, int K)
{
    __shared__ short ldsA[4096];  // 8 KB
    __shared__ short ldsB[4096];  // 8 KB

    const int t = threadIdx.x;
    const int l = t & 63;
    const int w = t >> 6;          // wave 0..3
    const int wr = w >> 1;         // wave row 0..1 (64-row half)
    const int wc = w & 1;          // wave col 0..1 (64-col half)
    const int m0 = blockIdx.y * 128;
    const int n0 = blockIdx.x * 128;

    const short* As = (const short*)A;
    const short* Bs = (const short*)B;

    const int g0 = w, rb0 = 0;
    const int g1 = w, rb1 = 64;

    const size_t arow0 = (size_t)(m0 + rb0 + l) * K;
    const size_t arow1 = (size_t)(m0 + rb1 + l) * K;
    const size_t brow0 = (size_t)(n0 + rb0 + l) * K;
    const size_t brow1 = (size_t)(n0 + rb1 + l) * K;
    const int lbase0 = g0 * 1024 + rb0 * 8;
    const int lbase1 = g1 * 1024 + rb1 * 8;

    const int fb = (l >> 4) * 1024 + (l & 15) * 8;
    const int fbA = fb + wr * 64 * 8;
    const int fbB = fb + wc * 64 * 8;

    f32x4 acc[4][4] = {};

    for (int k0 = 0; k0 < K; k0 += 32) {
        GL_LDS16(As + arow0 + k0 + g0 * 8, &ldsA[lbase0]);
        GL_LDS16(As + arow1 + k0 + g1 * 8, &ldsA[lbase1]);
        GL_LDS16(Bs + brow0 + k0 + g0 * 8, &ldsB[lbase0]);
        GL_LDS16(Bs + brow1 + k0 + g1 * 8, &ldsB[lbase1]);
        __syncthreads();

        s16x8 af[4], bf[4];
        #pragma unroll
        for (int mi = 0; mi < 4; ++mi)
            af[mi] = *(const s16x8*)&ldsA[fbA + mi * 16 * 8];
        #pragma unroll
        for (int ni = 0; ni < 4; ++ni)
            bf[ni] = *(const s16x8*)&ldsB[fbB + ni * 16 * 8];

        #pragma unroll
        for (int mi = 0; mi < 4; ++mi)
            #pragma unroll
            for (int ni = 0; ni < 4; ++ni)
                acc[mi][ni] = __builtin_amdgcn_mfma_f32_16x16x32_bf16(
                    af[mi], bf[ni], acc[mi][ni], 0, 0, 0);

        __syncthreads();
    }

    const int row0 = m0 + wr * 64 + (l >> 4) * 4;
    const int col0 = n0 + wc * 64 + (l & 15);
    #pragma unroll
    for (int ni = 0; ni < 4; ++ni) {
        const int n = col0 + ni * 16;
        const float bn = bias[n];
        #pragma unroll
        for (int mi = 0; mi < 4; ++mi) {
            const int r0 = row0 + mi * 16;
            #pragma unroll
            for (int r = 0; r < 4; ++r)
                C[(size_t)(r0 + r) * N + n] = (acc[mi][ni][r] + bn) * 0.2f;
        }
    }
}

// ============================ K0: f32 -> bf16 ==============================
__global__ __launch_bounds__(256) void f32_to_bf16(
    const float* __restrict__ in, __hip_bfloat16* __restrict__ out, int n4)
{
    int i = blockIdx.x * blockDim.x + threadIdx.x;
    const int stride = gridDim.x * blockDim.x;
    for (; i < n4; i += stride) {
        float4 v = ((const float4*)in)[i];
        __hip_bfloat16 o[4] = {
            __float2bfloat16(v.x), __float2bfloat16(v.y),
            __float2bfloat16(v.z), __float2bfloat16(v.w)};
        *(ushort4*)&out[(size_t)i * 4] = *(const ushort4*)o;
    }
}

// ===================== K1: small fp32 GEMM (NT) ============================
#define TILE_M 64
#define TILE_N 64
#define TILE_K 16
#define LDS_STRIDE 72

__global__ __launch_bounds__(256) void gemm_nt_lp(
    const float* __restrict__ A, const float* __restrict__ B,
    const float* __restrict__ bias, __hip_bfloat16* __restrict__ C,
    int M, int N, int K, int ldc)
{
    __shared__ float As[TILE_K][LDS_STRIDE];
    __shared__ float Bsh[TILE_K][LDS_STRIDE];

    const int t  = threadIdx.x;
    const int tx = t & 15;
    const int ty = t >> 4;
    const int m0 = blockIdx.y * TILE_M;
    const int n0 = blockIdx.x * TILE_N;
    const int lrow = t >> 2;
    const int lk   = (t & 3) << 2;

    float acc[4][4] = {};

    for (int kt = 0; kt < K; kt += TILE_K) {
        float4 av = *(const float4*)(A + (size_t)(m0 + lrow) * K + kt + lk);
        float4 bv = make_float4(0.f, 0.f, 0.f, 0.f);
        if (n0 + lrow < N)
            bv = *(const float4*)(B + (size_t)(n0 + lrow) * K + kt + lk);

        __syncthreads();
        As[lk + 0][lrow] = av.x; As[lk + 1][lrow] = av.y;
        As[lk + 2][lrow] = av.z; As[lk + 3][lrow] = av.w;
        Bsh[lk + 0][lrow] = bv.x; Bsh[lk + 1][lrow] = bv.y;
        Bsh[lk + 2][lrow] = bv.z; Bsh[lk + 3][lrow] = bv.w;
        __syncthreads();

        #pragma unroll
        for (int k = 0; k < TILE_K; ++k) {
            float4 a = *(const float4*)&As[k][ty << 2];
            float4 b = *(const float4*)&Bsh[k][tx << 2];
            acc[0][0] += a.x * b.x; acc[0][1] += a.x * b.y;
            acc[0][2] += a.x * b.z; acc[0][3] += a.x * b.w;
            acc[1][0] += a.y * b.x; acc[1][1] += a.y * b.y;
            acc[1][2] += a.y * b.z; acc[1][3] += a.y * b.w;
            acc[2][0] += a.z * b.x; acc[2][1] += a.z * b.y;
            acc[2][2] += a.z * b.z; acc[2][3] += a.z * b.w;
            acc[3][0] += a.w * b.x; acc[3][1] += a.w * b.y;
            acc[3][2] += a.w * b.z; acc[3][3] += a.w * b.w;
        }
    }

    #pragma unroll
    for (int j = 0; j < 4; ++j) {
        int n = n0 + (tx << 2) + j;
        if (n < N) {
            float bn = bias[n];
            #pragma unroll
            for (int i = 0; i < 4; ++i) {
                float v = (acc[i][j] + bn - 0.5f) / 0.2f;
                C[(size_t)(m0 + (ty << 2) + i) * ldc + n] = __float2bfloat16(v);
            }
        }
    }
}

// ===================== K2: restored half, bf16 =============================
__global__ __launch_bounds__(256) void build_restored(
    const float* __restrict__ xr, __hip_bfloat16* __restrict__ x)
{
    const int b = blockIdx.x;
    const int t = threadIdx.x;
    if (t < 196) {
        float4 v = *(const float4*)(xr + (size_t)b * 784 + (t << 2));
        __hip_bfloat16 o[4] = {
            __float2bfloat16((v.x - 0.5f) / 0.2f),
            __float2bfloat16((v.y - 0.5f) / 0.2f),
            __float2bfloat16((v.z - 0.5f) / 0.2f),
            __float2bfloat16((v.w - 0.5f) / 0.2f)};
        *(ushort4*)&x[(size_t)b * 1568 + 784 + (t << 2)] = *(const ushort4*)o;
    }
}

// ==================== K4a: Gram + Cholesky solve ===========================
// Per batch: G = W W^T via chunked MFMA (64-k bf16 chunks, swizzled LDS),
// L = chol(G), M = diag(L) * L^-1 -> Mws[b] (32x32 f32, row-major).
// Small LDS (~13 KB) => ~8 blocks/CU so the serial Cholesky/inversion
// latency overlaps across resident blocks.
#define GS_N 32
#define GS_D 784

__global__ __launch_bounds__(256, 4) void gram_solve(
    const float* __restrict__ out, float* __restrict__ Mws)
{
    __shared__ __align__(16) short Wc[GS_N * 64];   // 4 KB, XOR-swizzled
    __shared__ float Gs[GS_N][GS_N + 1];            // 4224 B (G -> L)
    __shared__ float Ms[GS_N][GS_N + 1];            // 4224 B
    __shared__ float Ld[GS_N];

    const int t = threadIdx.x;
    const int l = t & 63;
    const int w = t >> 6;
    const float* row0 = out + (size_t)blockIdx.x * (GS_N * GS_D);

    const int wr = w >> 1, wc2 = w & 1;
    const int ra = wr * 16 + (l & 15);
    const int rb = wc2 * 16 + (l & 15);
    const int kg = l >> 4;

    f32x4 acc = {};

    for (int k0 = 0; k0 < 832; k0 += 64) {   // 13 chunks, k >= 784 zero-pad
        #pragma unroll
        for (int hh = 0; hh < 2; ++hh) {
            const int h   = t + hh * 256;    // 0..511 = 32 rows x 16 qgrans
            const int r   = h >> 4;
            const int hg  = h & 15;          // quarter-granule (4 elems)
            const int col = k0 + (hg << 2);
            ushort4 u = make_ushort4(0, 0, 0, 0);
            if (col < GS_D) {
                float4 v = *(const float4*)(row0 + r * GS_D + col);
                __hip_bfloat16 hb[4] = {
                    __float2bfloat16(v.x), __float2bfloat16(v.y),
                    __float2bfloat16(v.z), __float2bfloat16(v.w)};
                u = *(const ushort4*)hb;
            }
            const int gp = (hg >> 1) ^ (r & 7);   // 16B-granule swizzle
            *(ushort4*)&Wc[(r << 6) + (gp << 3) + ((hg & 1) << 2)] = u;
        }
        __syncthreads();

        #pragma unroll
        for (int s = 0; s < 2; ++s) {
            const int ga = ((s << 2) + kg) ^ (ra & 7);
            const int gb = ((s << 2) + kg) ^ (rb & 7);
            s16x8 af = *(const s16x8*)&Wc[(ra << 6) + (ga << 3)];
            s16x8 bf = *(const s16x8*)&Wc[(rb << 6) + (gb << 3)];
            acc = __builtin_amdgcn_mfma_f32_16x16x32_bf16(af, bf, acc, 0, 0, 0);
        }
        __syncthreads();
    }

    // C/D layout: col = lane&15, row = (lane>>4)*4 + reg
    {
        const int di = wr * 16 + (l >> 4) * 4;
        const int dj = wc2 * 16 + (l & 15);
        #pragma unroll
        for (int r = 0; r < 4; ++r) Gs[di + r][dj] = acc[r];
    }
    // zero-init Ms (upper triangle otherwise uninitialized garbage)
    for (int z = t; z < GS_N * (GS_N + 1); z += 256) ((float*)Ms)[z] = 0.f;
    __syncthreads();

    // Cholesky, lower triangle in place (diag in Ld)
    for (int k = 0; k < GS_N; ++k) {
        const float sk = sqrtf(Gs[k][k]);
        if (t == k) Ld[k] = sk;
        if (t > k && t < GS_N) Gs[t][k] /= sk;
        __syncthreads();
        if (t > k && t < GS_N) {
            const float lik = Gs[t][k];
            for (int j = k + 1; j <= t; ++j)
                Gs[t][j] -= lik * Gs[j][k];
        }
        __syncthreads();
    }

    // M = diag(L) * L^-1, column-parallel forward substitution
    if (t < GS_N) {
        const int j = t;
        Ms[j][j] = 1.0f / Ld[j];
        for (int i = j + 1; i < GS_N; ++i) {
            float a = 0.f;
            for (int k = j; k < i; ++k)
                a += Gs[i][k] * Ms[k][j];
            Ms[i][j] = -a / Ld[i];
        }
        for (int i = j + 1; i < GS_N; ++i)
            Ms[i][j] *= Ld[i];
    }
    __syncthreads();

    // write compact [32][32] f32: thread t -> row t>>3, cols ((t&7)<<2)+0..3
    {
        const int i = t >> 3, j0 = (t & 7) << 2;
        float4 mv = make_float4(Ms[i][j0], Ms[i][j0 + 1],
                                Ms[i][j0 + 2], Ms[i][j0 + 3]);
        *(float4*)(Mws + (size_t)blockIdx.x * 1024 + (t << 2)) = mv;
    }
}

// ======================= K4b: apply correction =============================
// Block = (batch, 112-col chunk). out_i = w_i + sum_{j<i} M_ij * w_j, all
// f32 from LDS. 19 KB LDS, ~8 blocks/CU, no serial phases.
__global__ __launch_bounds__(256, 8) void gs_apply(
    float* __restrict__ out, const float* __restrict__ Mws)
{
    __shared__ float4 Wf[GS_N][28];     // 14336 B (f32 chunk)
    __shared__ float  Ml[GS_N][36];     // 4608 B (padded for f4 writes)

    const int t = threadIdx.x;
    const int b = blockIdx.y;
    const int k0 = blockIdx.x * 112;
    float* row0 = out + (size_t)b * (GS_N * GS_D);

    // stage M (1024 f32, one float4 per thread)
    {
        float4 mv = *(const float4*)(Mws + (size_t)b * 1024 + (t << 2));
        const int i = t >> 3, j0 = (t & 7) << 2;
        *(float4*)&Ml[i][j0] = mv;
    }
    // stage W chunk f32 (32 rows x 28 float4)
    #pragma unroll
    for (int hh = 0; hh < 4; ++hh) {
        const int h = t + hh * 256;     // 0..1023
        const int r = h >> 5, c = h & 31;
        if (c < 28)
            Wf[r][c] = *(const float4*)(row0 + r * GS_D + k0 + (c << 2));
    }
    __syncthreads();

    const int rg = t >> 5;              // row group: rows rg*4 .. rg*4+3
    const int c4 = t & 31;              // float4 column
    if (c4 < 28) {
        const int i0 = rg << 2;
        float4 c0 = Wf[i0 + 0][c4];
        float4 c1 = Wf[i0 + 1][c4];
        float4 c2 = Wf[i0 + 2][c4];
        float4 c3 = Wf[i0 + 3][c4];
        for (int j = 0; j < GS_N - 1; ++j) {
            if (j > i0 + 2) break;      // no row in this group has i > j
            const float4 wj = Wf[j][c4];
            const float m0 = (i0 + 0 > j) ? Ml[i0 + 0][j] : 0.f;
            const float m1 = (i0 + 1 > j) ? Ml[i0 + 1][j] : 0.f;
            const float m2 = (i0 + 2 > j) ? Ml[i0 + 2][j] : 0.f;
            const float m3 = (i0 + 3 > j) ? Ml[i0 + 3][j] : 0.f;
            c0.x += m0 * wj.x; c0.y += m0 * wj.y;
            c0.z += m0 * wj.z; c0.w += m0 * wj.w;
            c1.x += m1 * wj.x; c1.y += m1 * wj.y;
            c1.z += m1 * wj.z; c1.w += m1 * wj.w;
            c2.x += m2 * wj.x; c2.y += m2 * wj.y;
            c2.z += m2 * wj.z; c2.w += m2 * wj.w;
            c3.x += m3 * wj.x; c3.y += m3 * wj.y;
            c3.z += m3 * wj.z; c3.w += m3 * wj.w;
        }
        *(float4*)(row0 + (i0 + 0) * GS_D + k0 + (c4 << 2)) = c0;
        *(float4*)(row0 + (i0 + 1) * GS_D + k0 + (c4 << 2)) = c1;
        *(float4*)(row0 + (i0 + 2) * GS_D + k0 + (c4 << 2)) = c2;
        *(float4*)(row0 + (i0 + 3) * GS_D + k0 + (c4 << 2)) = c3;
    }
}

// ================================ launch ===================================
extern "C" void kernel_launch(void* const* d_in, const int* in_sizes, int n_in,
                              void* d_out, int out_size, void* d_ws, size_t ws_size,
                              hipStream_t stream)
{
    const float* xd   = (const float*)d_in[0];  // [2048, 832]
    const float* xr   = (const float*)d_in[1];  // [2048, 1, 28, 28]
    const float* Wlp  = (const float*)d_in[2];  // [784, 832]
    const float* blp  = (const float*)d_in[3];  // [784]
    const float* Wnet = (const float*)d_in[4];  // [25088, 1568]
    const float* bnet = (const float*)d_in[5];  // [25088]
    float* out = (float*)d_out;                 // [2048, 32, 784] f32

    const int B = 2048, IN_LP = 832, IMG = 784, IN_NET = 1568, OUT = 32 * 784;

    __hip_bfloat16* Wnet_bf = (__hip_bfloat16*)d_ws;
    __hip_bfloat16* x_bf =
        (__hip_bfloat16*)((char*)d_ws + (size_t)OUT * IN_NET * 2);
    // M workspace overlays Wnet_bf region (free after K3; stream-ordered).
    float* Mws = (float*)d_ws;                  // [2048][32][32] f32 = 8.4 MB

    // K0: W_net fp32 -> bf16
    f32_to_bf16<<<2048, 256, 0, stream>>>(Wnet, Wnet_bf, OUT * IN_NET / 4);

    // K1: linear projection + normalize -> bf16 x[:, :784]
    gemm_nt_lp<<<dim3((IMG + TILE_N - 1) / TILE_N, B / TILE_M), 256, 0, stream>>>(
        xd, Wlp, blp, x_bf, B, IMG, IN_LP, IN_NET);

    // K2: normalized restored image -> bf16 x[:, 784:]
    build_restored<<<B, 256, 0, stream>>>(xr, x_bf);

    // K3: big MFMA GEMM -> d_out (fp32)
    gemm_mfma_bf16<<<dim3(OUT / 128, B / 128), 256, 0, stream>>>(
        x_bf, Wnet_bf, bnet, out, B, OUT, IN_NET);

    // K4a: per-batch Gram + Cholesky -> M
    gram_solve<<<B, 256, 0, stream>>>(out, Mws);

    // K4b: apply rank-32 correction in place
    gs_apply<<<dim3(7, B), 256, 0, stream>>>(out, Mws);
}

// Round 3
// 477.836 us; speedup vs baseline: 2.0909x; 1.2131x over previous
//
#include <hip/hip_runtime.h>
#include <hip/hip_bf16.h>
#include <stdint.h>

// ---------------------------------------------------------------------------
// Pipeline:
//  K0 f32_to_bf16:    ws.Wnet_bf = bf16(W_net)                 [25088,1568]
//  K1 gemm_nt_lp:     ws.x_bf[:, :784] = bf16((xd@W_lp^T + b_lp - .5)/.2)
//  K2 build_restored: ws.x_bf[:, 784:] = bf16((x_restored - .5)/.2)
//  K3 gemm_mfma_256:  d_out = (x_bf @ Wnet_bf^T + b_net)*0.2   [2048,25088] f32
//                     256x256 tile, BK=32, 8 waves, 3-buffer LDS pipeline,
//                     counted vmcnt, XOR-swizzled LDS, XCD-banded blocks.
//  K4a gram_solve:    per batch: G = W W^T (chunked MFMA), L = chol(G),
//                     M = diag(L) L^-1  -> ws (reuses Wnet_bf region)
//  K4b gs_apply:      out_i = w_i + sum_{j<i} M_ij w_j  (chunked, f32)
// ---------------------------------------------------------------------------

typedef short s16x8 __attribute__((ext_vector_type(8)));
typedef float f32x4 __attribute__((ext_vector_type(4)));

#define GL_LDS16(gptr, lptr)                                                   \
    __builtin_amdgcn_global_load_lds(                                          \
        (const __attribute__((address_space(1))) void*)(gptr),                 \
        (__attribute__((address_space(3))) void*)(lptr), 16, 0, 0)

// ========================= K3: 256x256 MFMA GEMM ===========================
// C[m][n] = (sum_k A[m][k]*B[n][k] + bias[n]) * 0.2
// A: [M][K] bf16 row-major, B: [N][K] bf16 row-major. M%256==0, N%256==0,
// K%32==0. 512 threads = 8 waves (2 M-halves x 4 N-quarters); per-wave
// output 128x64 (8x4 16x16 frags). LDS: 3 buffers x (A 16KB + B 16KB),
// prefetch depth 2, one s_barrier + counted vmcnt(4) per K-step.
//
// LDS tile layout (per buffer half, [256 rows][32 bf16] = 64 B/row):
//   phys_byte = lin_byte ^ ((row & 12) << 2)   (XOR bits 4..5 w/ row bits 2..3)
// global_load_lds writes linearly (lane*16B), so the SOURCE global address is
// pre-swizzled; ds_read_b128 applies the same XOR (per-lane constant).
__global__ __launch_bounds__(512, 2) void gemm_mfma_256(
    const __hip_bfloat16* __restrict__ A, const __hip_bfloat16* __restrict__ B,
    const float* __restrict__ bias, float* __restrict__ C,
    int M, int N, int K)
{
    __shared__ __align__(16) short lds[3][16384];   // 96 KB

    const int t = threadIdx.x;
    const int l = t & 63;
    const int wv = t >> 6;          // wave 0..7
    const int wm = wv >> 2;         // M-half 0..1
    const int wn = wv & 3;          // N-quarter 0..3

    // XCD-banded mapping: XCD (f&7) owns output row-band yb, sweeps all xb.
    // A-band (256 x K bf16 ~ 800KB) stays L2-resident per XCD; B streams.
    const int f  = blockIdx.x;      // grid = 784 = 8 * 98, 8 | 784 (bijective)
    const int xb = f >> 3;
    const int yb = f & 7;
    const int m0 = yb * 256;
    const int n0 = xb * 256;

    const short* As = (const short*)A;
    const short* Bs = (const short*)B;

    // ---- staging source (per-lane, pre-swizzled) ----
    // slot s = 1024B = 16 rows; lane covers phys [s*1024 + l*16, +16):
    //   row  = s*16 + (l>>2)
    //   colE = (((l&3)<<4) ^ (l&48)) >> 1   (logical element offset)
    const int colE = ((((l & 3) << 4) ^ (l & 48)) >> 1);
    const size_t baseA0 = (size_t)(m0 + wv * 32 +  0 + (l >> 2)) * K + colE;
    const size_t baseA1 = (size_t)(m0 + wv * 32 + 16 + (l >> 2)) * K + colE;
    const size_t baseB0 = (size_t)(n0 + wv * 32 +  0 + (l >> 2)) * K + colE;
    const size_t baseB1 = (size_t)(n0 + wv * 32 + 16 + (l >> 2)) * K + colE;
    const int dst0 = (wv * 2 + 0) * 512;    // LDS dest (shorts)
    const int dst1 = (wv * 2 + 1) * 512;

    // ---- fragment read offsets (shorts); XOR folds to per-lane constant ----
    const int xk   = ((l >> 4) * 16) ^ ((l & 12) << 2);          // bytes
    const int aoff = ((wm * 128 + (l & 15)) * 64 + xk) >> 1;
    const int boff = ((wn * 64  + (l & 15)) * 64 + xk) >> 1;

    f32x4 acc[8][4] = {};

#define STAGE_TILE(buf, T)                                                     \
    do {                                                                       \
        short* bA_ = &lds[buf][0];                                             \
        short* bB_ = &lds[buf][8192];                                          \
        const size_t ko_ = (size_t)(T) * 32;                                   \
        GL_LDS16(As + baseA0 + ko_, bA_ + dst0);                               \
        GL_LDS16(As + baseA1 + ko_, bA_ + dst1);                               \
        GL_LDS16(Bs + baseB0 + ko_, bB_ + dst0);                               \
        GL_LDS16(Bs + baseB1 + ko_, bB_ + dst1);                               \
    } while (0)

    const int NT = K >> 5;          // 49
    STAGE_TILE(0, 0);
    STAGE_TILE(1, 1);

    int cur = 0;
    for (int kt = 0; kt < NT; ++kt) {
        // wait only for tile kt's loads (issued 2 iters ago); tile kt+1's
        // 4 loads stay in flight (counted vmcnt, T4).
        if (kt < NT - 1) asm volatile("s_waitcnt vmcnt(4)");
        else             asm volatile("s_waitcnt vmcnt(0)");
        __builtin_amdgcn_sched_barrier(0);
        asm volatile("" ::: "memory");
        __builtin_amdgcn_s_barrier();
        asm volatile("" ::: "memory");
        __builtin_amdgcn_sched_barrier(0);
        // Single-barrier safety: STAGE target buf (kt+2)%3 == (kt-1)%3 was
        // last read at iter kt-1, which completed before this barrier.

        if (kt + 2 < NT) {
            int nb = cur + 2; if (nb >= 3) nb -= 3;
            STAGE_TILE(nb, kt + 2);
        }

        const short* bA = &lds[cur][0];
        const short* bB = &lds[cur][8192];
        s16x8 af[8], bf[4];
        #pragma unroll
        for (int mi = 0; mi < 8; ++mi)
            af[mi] = *(const s16x8*)&bA[aoff + mi * 512];
        #pragma unroll
        for (int ni = 0; ni < 4; ++ni)
            bf[ni] = *(const s16x8*)&bB[boff + ni * 512];

        __builtin_amdgcn_s_setprio(1);
        #pragma unroll
        for (int mi = 0; mi < 8; ++mi)
            #pragma unroll
            for (int ni = 0; ni < 4; ++ni)
                acc[mi][ni] = __builtin_amdgcn_mfma_f32_16x16x32_bf16(
                    af[mi], bf[ni], acc[mi][ni], 0, 0, 0);
        __builtin_amdgcn_s_setprio(0);

        ++cur; if (cur >= 3) cur = 0;
    }
#undef STAGE_TILE

    // ---- epilogue: C/D layout col = lane&15, row = (lane>>4)*4 + reg ----
    const int row0 = m0 + wm * 128 + ((l >> 4) << 2);
    const int col0 = n0 + wn * 64 + (l & 15);
    #pragma unroll
    for (int ni = 0; ni < 4; ++ni) {
        const int n = col0 + ni * 16;
        const float bn = bias[n];
        #pragma unroll
        for (int mi = 0; mi < 8; ++mi) {
            const int r0 = row0 + mi * 16;
            #pragma unroll
            for (int r = 0; r < 4; ++r)
                C[(size_t)(r0 + r) * N + n] = (acc[mi][ni][r] + bn) * 0.2f;
        }
    }
}

// ============================ K0: f32 -> bf16 ==============================
__global__ __launch_bounds__(256) void f32_to_bf16(
    const float* __restrict__ in, __hip_bfloat16* __restrict__ out, int n4)
{
    int i = blockIdx.x * blockDim.x + threadIdx.x;
    const int stride = gridDim.x * blockDim.x;
    for (; i < n4; i += stride) {
        float4 v = ((const float4*)in)[i];
        __hip_bfloat16 o[4] = {
            __float2bfloat16(v.x), __float2bfloat16(v.y),
            __float2bfloat16(v.z), __float2bfloat16(v.w)};
        *(ushort4*)&out[(size_t)i * 4] = *(const ushort4*)o;
    }
}

// ===================== K1: small fp32 GEMM (NT) ============================
#define TILE_M 64
#define TILE_N 64
#define TILE_K 16
#define LDS_STRIDE 72

__global__ __launch_bounds__(256) void gemm_nt_lp(
    const float* __restrict__ A, const float* __restrict__ B,
    const float* __restrict__ bias, __hip_bfloat16* __restrict__ C,
    int M, int N, int K, int ldc)
{
    __shared__ float As[TILE_K][LDS_STRIDE];
    __shared__ float Bsh[TILE_K][LDS_STRIDE];

    const int t  = threadIdx.x;
    const int tx = t & 15;
    const int ty = t >> 4;
    const int m0 = blockIdx.y * TILE_M;
    const int n0 = blockIdx.x * TILE_N;
    const int lrow = t >> 2;
    const int lk   = (t & 3) << 2;

    float acc[4][4] = {};

    for (int kt = 0; kt < K; kt += TILE_K) {
        float4 av = *(const float4*)(A + (size_t)(m0 + lrow) * K + kt + lk);
        float4 bv = make_float4(0.f, 0.f, 0.f, 0.f);
        if (n0 + lrow < N)
            bv = *(const float4*)(B + (size_t)(n0 + lrow) * K + kt + lk);

        __syncthreads();
        As[lk + 0][lrow] = av.x; As[lk + 1][lrow] = av.y;
        As[lk + 2][lrow] = av.z; As[lk + 3][lrow] = av.w;
        Bsh[lk + 0][lrow] = bv.x; Bsh[lk + 1][lrow] = bv.y;
        Bsh[lk + 2][lrow] = bv.z; Bsh[lk + 3][lrow] = bv.w;
        __syncthreads();

        #pragma unroll
        for (int k = 0; k < TILE_K; ++k) {
            float4 a = *(const float4*)&As[k][ty << 2];
            float4 b = *(const float4*)&Bsh[k][tx << 2];
            acc[0][0] += a.x * b.x; acc[0][1] += a.x * b.y;
            acc[0][2] += a.x * b.z; acc[0][3] += a.x * b.w;
            acc[1][0] += a.y * b.x; acc[1][1] += a.y * b.y;
            acc[1][2] += a.y * b.z; acc[1][3] += a.y * b.w;
            acc[2][0] += a.z * b.x; acc[2][1] += a.z * b.y;
            acc[2][2] += a.z * b.z; acc[2][3] += a.z * b.w;
            acc[3][0] += a.w * b.x; acc[3][1] += a.w * b.y;
            acc[3][2] += a.w * b.z; acc[3][3] += a.w * b.w;
        }
    }

    #pragma unroll
    for (int j = 0; j < 4; ++j) {
        int n = n0 + (tx << 2) + j;
        if (n < N) {
            float bn = bias[n];
            #pragma unroll
            for (int i = 0; i < 4; ++i) {
                float v = (acc[i][j] + bn - 0.5f) / 0.2f;
                C[(size_t)(m0 + (ty << 2) + i) * ldc + n] = __float2bfloat16(v);
            }
        }
    }
}

// ===================== K2: restored half, bf16 =============================
__global__ __launch_bounds__(256) void build_restored(
    const float* __restrict__ xr, __hip_bfloat16* __restrict__ x)
{
    const int b = blockIdx.x;
    const int t = threadIdx.x;
    if (t < 196) {
        float4 v = *(const float4*)(xr + (size_t)b * 784 + (t << 2));
        __hip_bfloat16 o[4] = {
            __float2bfloat16((v.x - 0.5f) / 0.2f),
            __float2bfloat16((v.y - 0.5f) / 0.2f),
            __float2bfloat16((v.z - 0.5f) / 0.2f),
            __float2bfloat16((v.w - 0.5f) / 0.2f)};
        *(ushort4*)&x[(size_t)b * 1568 + 784 + (t << 2)] = *(const ushort4*)o;
    }
}

// ==================== K4a: Gram + Cholesky solve ===========================
// Per batch: G = W W^T via chunked MFMA (64-k bf16 chunks, swizzled LDS),
// L = chol(G), M = diag(L) * L^-1 -> Mws[b] (32x32 f32, row-major).
#define GS_N 32
#define GS_D 784

__global__ __launch_bounds__(256, 4) void gram_solve(
    const float* __restrict__ out, float* __restrict__ Mws)
{
    __shared__ __align__(16) short Wc[GS_N * 64];   // 4 KB, XOR-swizzled
    __shared__ float Gs[GS_N][GS_N + 1];            // 4224 B (G -> L)
    __shared__ float Ms[GS_N][GS_N + 1];            // 4224 B
    __shared__ float Ld[GS_N];

    const int t = threadIdx.x;
    const int l = t & 63;
    const int w = t >> 6;
    const float* row0 = out + (size_t)blockIdx.x * (GS_N * GS_D);

    const int wr = w >> 1, wc2 = w & 1;
    const int ra = wr * 16 + (l & 15);
    const int rb = wc2 * 16 + (l & 15);
    const int kg = l >> 4;

    f32x4 acc = {};

    for (int k0 = 0; k0 < 832; k0 += 64) {   // 13 chunks, k >= 784 zero-pad
        #pragma unroll
        for (int hh = 0; hh < 2; ++hh) {
            const int h   = t + hh * 256;    // 0..511 = 32 rows x 16 qgrans
            const int r   = h >> 4;
            const int hg  = h & 15;          // quarter-granule (4 elems)
            const int col = k0 + (hg << 2);
            ushort4 u = make_ushort4(0, 0, 0, 0);
            if (col < GS_D) {
                float4 v = *(const float4*)(row0 + r * GS_D + col);
                __hip_bfloat16 hb[4] = {
                    __float2bfloat16(v.x), __float2bfloat16(v.y),
                    __float2bfloat16(v.z), __float2bfloat16(v.w)};
                u = *(const ushort4*)hb;
            }
            const int gp = (hg >> 1) ^ (r & 7);   // 16B-granule swizzle
            *(ushort4*)&Wc[(r << 6) + (gp << 3) + ((hg & 1) << 2)] = u;
        }
        __syncthreads();

        #pragma unroll
        for (int s = 0; s < 2; ++s) {
            const int ga = ((s << 2) + kg) ^ (ra & 7);
            const int gb = ((s << 2) + kg) ^ (rb & 7);
            s16x8 af = *(const s16x8*)&Wc[(ra << 6) + (ga << 3)];
            s16x8 bf = *(const s16x8*)&Wc[(rb << 6) + (gb << 3)];
            acc = __builtin_amdgcn_mfma_f32_16x16x32_bf16(af, bf, acc, 0, 0, 0);
        }
        __syncthreads();
    }

    {
        const int di = wr * 16 + (l >> 4) * 4;
        const int dj = wc2 * 16 + (l & 15);
        #pragma unroll
        for (int r = 0; r < 4; ++r) Gs[di + r][dj] = acc[r];
    }
    for (int z = t; z < GS_N * (GS_N + 1); z += 256) ((float*)Ms)[z] = 0.f;
    __syncthreads();

    // Cholesky, lower triangle in place (diag in Ld)
    for (int k = 0; k < GS_N; ++k) {
        const float sk = sqrtf(Gs[k][k]);
        if (t == k) Ld[k] = sk;
        if (t > k && t < GS_N) Gs[t][k] /= sk;
        __syncthreads();
        if (t > k && t < GS_N) {
            const float lik = Gs[t][k];
            for (int j = k + 1; j <= t; ++j)
                Gs[t][j] -= lik * Gs[j][k];
        }
        __syncthreads();
    }

    // M = diag(L) * L^-1, column-parallel forward substitution
    if (t < GS_N) {
        const int j = t;
        Ms[j][j] = 1.0f / Ld[j];
        for (int i = j + 1; i < GS_N; ++i) {
            float a = 0.f;
            for (int k = j; k < i; ++k)
                a += Gs[i][k] * Ms[k][j];
            Ms[i][j] = -a / Ld[i];
        }
        for (int i = j + 1; i < GS_N; ++i)
            Ms[i][j] *= Ld[i];
    }
    __syncthreads();

    {
        const int i = t >> 3, j0 = (t & 7) << 2;
        float4 mv = make_float4(Ms[i][j0], Ms[i][j0 + 1],
                                Ms[i][j0 + 2], Ms[i][j0 + 3]);
        *(float4*)(Mws + (size_t)blockIdx.x * 1024 + (t << 2)) = mv;
    }
}

// ======================= K4b: apply correction =============================
__global__ __launch_bounds__(256, 8) void gs_apply(
    float* __restrict__ out, const float* __restrict__ Mws)
{
    __shared__ float4 Wf[GS_N][28];     // 14336 B (f32 chunk)
    __shared__ float  Ml[GS_N][36];     // 4608 B (padded for f4 writes)

    const int t = threadIdx.x;
    const int b = blockIdx.y;
    const int k0 = blockIdx.x * 112;
    float* row0 = out + (size_t)b * (GS_N * GS_D);

    {
        float4 mv = *(const float4*)(Mws + (size_t)b * 1024 + (t << 2));
        const int i = t >> 3, j0 = (t & 7) << 2;
        *(float4*)&Ml[i][j0] = mv;
    }
    #pragma unroll
    for (int hh = 0; hh < 4; ++hh) {
        const int h = t + hh * 256;     // 0..1023
        const int r = h >> 5, c = h & 31;
        if (c < 28)
            Wf[r][c] = *(const float4*)(row0 + r * GS_D + k0 + (c << 2));
    }
    __syncthreads();

    const int rg = t >> 5;              // row group: rows rg*4 .. rg*4+3
    const int c4 = t & 31;              // float4 column
    if (c4 < 28) {
        const int i0 = rg << 2;
        float4 c0 = Wf[i0 + 0][c4];
        float4 c1 = Wf[i0 + 1][c4];
        float4 c2 = Wf[i0 + 2][c4];
        float4 c3 = Wf[i0 + 3][c4];
        for (int j = 0; j < GS_N - 1; ++j) {
            if (j > i0 + 2) break;
            const float4 wj = Wf[j][c4];
            const float m0 = (i0 + 0 > j) ? Ml[i0 + 0][j] : 0.f;
            const float m1 = (i0 + 1 > j) ? Ml[i0 + 1][j] : 0.f;
            const float m2 = (i0 + 2 > j) ? Ml[i0 + 2][j] : 0.f;
            const float m3 = (i0 + 3 > j) ? Ml[i0 + 3][j] : 0.f;
            c0.x += m0 * wj.x; c0.y += m0 * wj.y;
            c0.z += m0 * wj.z; c0.w += m0 * wj.w;
            c1.x += m1 * wj.x; c1.y += m1 * wj.y;
            c1.z += m1 * wj.z; c1.w += m1 * wj.w;
            c2.x += m2 * wj.x; c2.y += m2 * wj.y;
            c2.z += m2 * wj.z; c2.w += m2 * wj.w;
            c3.x += m3 * wj.x; c3.y += m3 * wj.y;
            c3.z += m3 * wj.z; c3.w += m3 * wj.w;
        }
        *(float4*)(row0 + (i0 + 0) * GS_D + k0 + (c4 << 2)) = c0;
        *(float4*)(row0 + (i0 + 1) * GS_D + k0 + (c4 << 2)) = c1;
        *(float4*)(row0 + (i0 + 2) * GS_D + k0 + (c4 << 2)) = c2;
        *(float4*)(row0 + (i0 + 3) * GS_D + k0 + (c4 << 2)) = c3;
    }
}

// ================================ launch ===================================
extern "C" void kernel_launch(void* const* d_in, const int* in_sizes, int n_in,
                              void* d_out, int out_size, void* d_ws, size_t ws_size,
                              hipStream_t stream)
{
    const float* xd   = (const float*)d_in[0];  // [2048, 832]
    const float* xr   = (const float*)d_in[1];  // [2048, 1, 28, 28]
    const float* Wlp  = (const float*)d_in[2];  // [784, 832]
    const float* blp  = (const float*)d_in[3];  // [784]
    const float* Wnet = (const float*)d_in[4];  // [25088, 1568]
    const float* bnet = (const float*)d_in[5];  // [25088]
    float* out = (float*)d_out;                 // [2048, 32, 784] f32

    const int B = 2048, IN_LP = 832, IMG = 784, IN_NET = 1568, OUT = 32 * 784;

    __hip_bfloat16* Wnet_bf = (__hip_bfloat16*)d_ws;
    __hip_bfloat16* x_bf =
        (__hip_bfloat16*)((char*)d_ws + (size_t)OUT * IN_NET * 2);
    // M workspace overlays Wnet_bf region (free after K3; stream-ordered).
    float* Mws = (float*)d_ws;                  // [2048][32][32] f32 = 8.4 MB

    // K0: W_net fp32 -> bf16
    f32_to_bf16<<<2048, 256, 0, stream>>>(Wnet, Wnet_bf, OUT * IN_NET / 4);

    // K1: linear projection + normalize -> bf16 x[:, :784]
    gemm_nt_lp<<<dim3((IMG + TILE_N - 1) / TILE_N, B / TILE_M), 256, 0, stream>>>(
        xd, Wlp, blp, x_bf, B, IMG, IN_LP, IN_NET);

    // K2: normalized restored image -> bf16 x[:, 784:]
    build_restored<<<B, 256, 0, stream>>>(xr, x_bf);

    // K3: big MFMA GEMM -> d_out (fp32); grid 784 = 8 XCD bands x 98
    gemm_mfma_256<<<dim3(784), 512, 0, stream>>>(
        x_bf, Wnet_bf, bnet, out, B, OUT, IN_NET);

    // K4a: per-batch Gram + Cholesky -> M
    gram_solve<<<B, 256, 0, stream>>>(out, Mws);

    // K4b: apply rank-32 correction in place
    gs_apply<<<dim3(7, B), 256, 0, stream>>>(out, Mws);
}

// Round 4
// 463.824 us; speedup vs baseline: 2.1540x; 1.0302x over previous
//
#include <hip/hip_runtime.h>
#include <hip/hip_bf16.h>
#include <stdint.h>

// ---------------------------------------------------------------------------
// Pipeline:
//  K0 f32_to_bf16:    ws.Wnet_bf = bf16(W_net)                 [25088,1568]
//  K1 gemm_nt_lp:     ws.x_bf[:, :784] = bf16((xd@W_lp^T + b_lp - .5)/.2)
//  K2 build_restored: ws.x_bf[:, 784:] = bf16((x_restored - .5)/.2)
//  K3 gemm_mfma_256:  d_out = (x_bf @ Wnet_bf^T + b_net)*0.2   [2048,25088] f32
//                     256x256 tile, BK=32, 8 waves, 4-buffer LDS pipeline
//                     (depth 3, counted vmcnt(8)), XOR-swizzled LDS
//                     (row bits 1-2 -> byte bits 4-5), XCD-banded blocks.
//  K4a gram_solve:    per batch: G = W W^T (chunked MFMA), L = chol(G),
//                     M = diag(L) L^-1  -> ws (reuses Wnet_bf region)
//  K4b gs_apply:      out_i = w_i + sum_{j<i} M_ij w_j  (chunked, f32)
// ---------------------------------------------------------------------------

typedef short s16x8 __attribute__((ext_vector_type(8)));
typedef float f32x4 __attribute__((ext_vector_type(4)));

#define GL_LDS16(gptr, lptr)                                                   \
    __builtin_amdgcn_global_load_lds(                                          \
        (const __attribute__((address_space(1))) void*)(gptr),                 \
        (__attribute__((address_space(3))) void*)(lptr), 16, 0, 0)

// ========================= K3: 256x256 MFMA GEMM ===========================
// C[m][n] = (sum_k A[m][k]*B[n][k] + bias[n]) * 0.2
// A: [M][K] bf16 row-major, B: [N][K] bf16 row-major. M%256==0, N%256==0,
// K%32==0. 512 threads = 8 waves (2 M-halves x 4 N-quarters); per-wave
// output 128x64 (8x4 16x16 frags). LDS: 4 buffers x (A 8KB + B 8KB),
// prefetch depth 3, one s_barrier + counted vmcnt(8) per K-step.
//
// LDS tile layout (per buffer half, [256 rows][32 bf16] = 64 B/row):
//   phys_byte = lin_byte ^ ((row & 6) << 3)
// Bank(first word) = 16*(row&1) + 4*(kg ^ ((row>>1)&3)) -> max 2 lanes/bank
// per cycle on ds_read_b128 (2-way is free, m136). global_load_lds writes
// linearly (lane*16B), so the SOURCE global address is pre-swizzled; the
// ds_read_b128 address applies the same XOR (folds to a per-lane constant).
__global__ __launch_bounds__(512, 2) void gemm_mfma_256(
    const __hip_bfloat16* __restrict__ A, const __hip_bfloat16* __restrict__ B,
    const float* __restrict__ bias, float* __restrict__ C,
    int M, int N, int K)
{
    __shared__ __align__(16) short lds[4][16384];   // 128 KB

    const int t = threadIdx.x;
    const int l = t & 63;
    const int wv = t >> 6;          // wave 0..7
    const int wm = wv >> 2;         // M-half 0..1
    const int wn = wv & 3;          // N-quarter 0..3

    // XCD-banded mapping: XCD (f&7) owns output row-band yb, sweeps all xb.
    // A-band (256 x K bf16 ~ 800KB) stays L2-resident per XCD; B streams.
    const int f  = blockIdx.x;      // grid = 784 = 8 * 98, 8 | 784 (bijective)
    const int xb = f >> 3;
    const int yb = f & 7;
    const int m0 = yb * 256;
    const int n0 = xb * 256;

    const short* As = (const short*)A;
    const short* Bs = (const short*)B;

    // ---- staging source (per-lane, pre-swizzled) ----
    // lane covers phys bytes [l*16, +16) of its wave's 1024B slot:
    //   phys_row = slot*16 + (l>>2), phys in-row byte = (l&3)*16
    //   lin colByte = (l&3)*16 ^ ((phys_row & 6) << 3) = (l&3)*16 ^ (l&24)*2
    const int colE = ((((l & 3) << 4) ^ ((l & 24) << 1)) >> 1);
    const size_t baseA0 = (size_t)(m0 + wv * 32 +  0 + (l >> 2)) * K + colE;
    const size_t baseA1 = (size_t)(m0 + wv * 32 + 16 + (l >> 2)) * K + colE;
    const size_t baseB0 = (size_t)(n0 + wv * 32 +  0 + (l >> 2)) * K + colE;
    const size_t baseB1 = (size_t)(n0 + wv * 32 + 16 + (l >> 2)) * K + colE;
    const int dst0 = (wv * 2 + 0) * 512;    // LDS dest (shorts)
    const int dst1 = (wv * 2 + 1) * 512;

    // ---- fragment read offsets (shorts); XOR folds to per-lane constant ----
    // frag row = base16 + (l&15); (row&6)==(l&6) since base16 is mult of 16.
    const int xk   = ((l >> 4) * 16) ^ ((l & 6) << 3);           // bytes
    const int aoff = ((wm * 128 + (l & 15)) * 64 + xk) >> 1;
    const int boff = ((wn * 64  + (l & 15)) * 64 + xk) >> 1;

    f32x4 acc[8][4] = {};

#define STAGE_TILE(buf, T)                                                     \
    do {                                                                       \
        short* bA_ = &lds[buf][0];                                             \
        short* bB_ = &lds[buf][8192];                                          \
        const size_t ko_ = (size_t)(T) * 32;                                   \
        GL_LDS16(As + baseA0 + ko_, bA_ + dst0);                               \
        GL_LDS16(As + baseA1 + ko_, bA_ + dst1);                               \
        GL_LDS16(Bs + baseB0 + ko_, bB_ + dst0);                               \
        GL_LDS16(Bs + baseB1 + ko_, bB_ + dst1);                               \
    } while (0)

    const int NT = K >> 5;          // 49
    STAGE_TILE(0, 0);
    STAGE_TILE(1, 1);
    STAGE_TILE(2, 2);

    for (int kt = 0; kt < NT; ++kt) {
        const int cur = kt & 3;
        // wait only for tile kt's 4 loads; tiles kt+1, kt+2 (8 loads) stay
        // in flight across the barrier (counted vmcnt, T4).
        if (kt < NT - 2)      asm volatile("s_waitcnt vmcnt(8)");
        else if (kt == NT - 2) asm volatile("s_waitcnt vmcnt(4)");
        else                  asm volatile("s_waitcnt vmcnt(0)");
        __builtin_amdgcn_sched_barrier(0);
        asm volatile("" ::: "memory");
        __builtin_amdgcn_s_barrier();
        asm volatile("" ::: "memory");
        __builtin_amdgcn_sched_barrier(0);
        // Single-barrier safety: STAGE target buf (kt+3)&3 == (kt-1)&3 was
        // last read at iter kt-1, which completed before this barrier.

        if (kt + 3 < NT) STAGE_TILE((kt + 3) & 3, kt + 3);

        const short* bA = &lds[cur][0];
        const short* bB = &lds[cur][8192];
        s16x8 af[8], bf[4];
        #pragma unroll
        for (int mi = 0; mi < 8; ++mi)
            af[mi] = *(const s16x8*)&bA[aoff + mi * 512];
        #pragma unroll
        for (int ni = 0; ni < 4; ++ni)
            bf[ni] = *(const s16x8*)&bB[boff + ni * 512];

        __builtin_amdgcn_s_setprio(1);
        #pragma unroll
        for (int mi = 0; mi < 8; ++mi)
            #pragma unroll
            for (int ni = 0; ni < 4; ++ni)
                acc[mi][ni] = __builtin_amdgcn_mfma_f32_16x16x32_bf16(
                    af[mi], bf[ni], acc[mi][ni], 0, 0, 0);
        __builtin_amdgcn_s_setprio(0);
    }
#undef STAGE_TILE

    // ---- epilogue: C/D layout col = lane&15, row = (lane>>4)*4 + reg ----
    const int row0 = m0 + wm * 128 + ((l >> 4) << 2);
    const int col0 = n0 + wn * 64 + (l & 15);
    #pragma unroll
    for (int ni = 0; ni < 4; ++ni) {
        const int n = col0 + ni * 16;
        const float bn = bias[n];
        #pragma unroll
        for (int mi = 0; mi < 8; ++mi) {
            const int r0 = row0 + mi * 16;
            #pragma unroll
            for (int r = 0; r < 4; ++r)
                C[(size_t)(r0 + r) * N + n] = (acc[mi][ni][r] + bn) * 0.2f;
        }
    }
}

// ============================ K0: f32 -> bf16 ==============================
__global__ __launch_bounds__(256) void f32_to_bf16(
    const float* __restrict__ in, __hip_bfloat16* __restrict__ out, int n4)
{
    int i = blockIdx.x * blockDim.x + threadIdx.x;
    const int stride = gridDim.x * blockDim.x;
    for (; i < n4; i += stride) {
        float4 v = ((const float4*)in)[i];
        __hip_bfloat16 o[4] = {
            __float2bfloat16(v.x), __float2bfloat16(v.y),
            __float2bfloat16(v.z), __float2bfloat16(v.w)};
        *(ushort4*)&out[(size_t)i * 4] = *(const ushort4*)o;
    }
}

// ===================== K1: small fp32 GEMM (NT) ============================
#define TILE_M 64
#define TILE_N 64
#define TILE_K 16
#define LDS_STRIDE 72

__global__ __launch_bounds__(256) void gemm_nt_lp(
    const float* __restrict__ A, const float* __restrict__ B,
    const float* __restrict__ bias, __hip_bfloat16* __restrict__ C,
    int M, int N, int K, int ldc)
{
    __shared__ float As[TILE_K][LDS_STRIDE];
    __shared__ float Bsh[TILE_K][LDS_STRIDE];

    const int t  = threadIdx.x;
    const int tx = t & 15;
    const int ty = t >> 4;
    const int m0 = blockIdx.y * TILE_M;
    const int n0 = blockIdx.x * TILE_N;
    const int lrow = t >> 2;
    const int lk   = (t & 3) << 2;

    float acc[4][4] = {};

    for (int kt = 0; kt < K; kt += TILE_K) {
        float4 av = *(const float4*)(A + (size_t)(m0 + lrow) * K + kt + lk);
        float4 bv = make_float4(0.f, 0.f, 0.f, 0.f);
        if (n0 + lrow < N)
            bv = *(const float4*)(B + (size_t)(n0 + lrow) * K + kt + lk);

        __syncthreads();
        As[lk + 0][lrow] = av.x; As[lk + 1][lrow] = av.y;
        As[lk + 2][lrow] = av.z; As[lk + 3][lrow] = av.w;
        Bsh[lk + 0][lrow] = bv.x; Bsh[lk + 1][lrow] = bv.y;
        Bsh[lk + 2][lrow] = bv.z; Bsh[lk + 3][lrow] = bv.w;
        __syncthreads();

        #pragma unroll
        for (int k = 0; k < TILE_K; ++k) {
            float4 a = *(const float4*)&As[k][ty << 2];
            float4 b = *(const float4*)&Bsh[k][tx << 2];
            acc[0][0] += a.x * b.x; acc[0][1] += a.x * b.y;
            acc[0][2] += a.x * b.z; acc[0][3] += a.x * b.w;
            acc[1][0] += a.y * b.x; acc[1][1] += a.y * b.y;
            acc[1][2] += a.y * b.z; acc[1][3] += a.y * b.w;
            acc[2][0] += a.z * b.x; acc[2][1] += a.z * b.y;
            acc[2][2] += a.z * b.z; acc[2][3] += a.z * b.w;
            acc[3][0] += a.w * b.x; acc[3][1] += a.w * b.y;
            acc[3][2] += a.w * b.z; acc[3][3] += a.w * b.w;
        }
    }

    #pragma unroll
    for (int j = 0; j < 4; ++j) {
        int n = n0 + (tx << 2) + j;
        if (n < N) {
            float bn = bias[n];
            #pragma unroll
            for (int i = 0; i < 4; ++i) {
                float v = (acc[i][j] + bn - 0.5f) / 0.2f;
                C[(size_t)(m0 + (ty << 2) + i) * ldc + n] = __float2bfloat16(v);
            }
        }
    }
}

// ===================== K2: restored half, bf16 =============================
__global__ __launch_bounds__(256) void build_restored(
    const float* __restrict__ xr, __hip_bfloat16* __restrict__ x)
{
    const int b = blockIdx.x;
    const int t = threadIdx.x;
    if (t < 196) {
        float4 v = *(const float4*)(xr + (size_t)b * 784 + (t << 2));
        __hip_bfloat16 o[4] = {
            __float2bfloat16((v.x - 0.5f) / 0.2f),
            __float2bfloat16((v.y - 0.5f) / 0.2f),
            __float2bfloat16((v.z - 0.5f) / 0.2f),
            __float2bfloat16((v.w - 0.5f) / 0.2f)};
        *(ushort4*)&x[(size_t)b * 1568 + 784 + (t << 2)] = *(const ushort4*)o;
    }
}

// ==================== K4a: Gram + Cholesky solve ===========================
// Per batch: G = W W^T via chunked MFMA (64-k bf16 chunks, swizzled LDS),
// L = chol(G), M = diag(L) * L^-1 -> Mws[b] (32x32 f32, row-major).
#define GS_N 32
#define GS_D 784

__global__ __launch_bounds__(256, 4) void gram_solve(
    const float* __restrict__ out, float* __restrict__ Mws)
{
    __shared__ __align__(16) short Wc[GS_N * 64];   // 4 KB, XOR-swizzled
    __shared__ float Gs[GS_N][GS_N + 1];            // 4224 B (G -> L)
    __shared__ float Ms[GS_N][GS_N + 1];            // 4224 B
    __shared__ float Ld[GS_N];

    const int t = threadIdx.x;
    const int l = t & 63;
    const int w = t >> 6;
    const float* row0 = out + (size_t)blockIdx.x * (GS_N * GS_D);

    const int wr = w >> 1, wc2 = w & 1;
    const int ra = wr * 16 + (l & 15);
    const int rb = wc2 * 16 + (l & 15);
    const int kg = l >> 4;

    f32x4 acc = {};

    for (int k0 = 0; k0 < 832; k0 += 64) {   // 13 chunks, k >= 784 zero-pad
        #pragma unroll
        for (int hh = 0; hh < 2; ++hh) {
            const int h   = t + hh * 256;    // 0..511 = 32 rows x 16 qgrans
            const int r   = h >> 4;
            const int hg  = h & 15;          // quarter-granule (4 elems)
            const int col = k0 + (hg << 2);
            ushort4 u = make_ushort4(0, 0, 0, 0);
            if (col < GS_D) {
                float4 v = *(const float4*)(row0 + r * GS_D + col);
                __hip_bfloat16 hb[4] = {
                    __float2bfloat16(v.x), __float2bfloat16(v.y),
                    __float2bfloat16(v.z), __float2bfloat16(v.w)};
                u = *(const ushort4*)hb;
            }
            const int gp = (hg >> 1) ^ (r & 7);   // 16B-granule swizzle
            *(ushort4*)&Wc[(r << 6) + (gp << 3) + ((hg & 1) << 2)] = u;
        }
        __syncthreads();

        #pragma unroll
        for (int s = 0; s < 2; ++s) {
            const int ga = ((s << 2) + kg) ^ (ra & 7);
            const int gb = ((s << 2) + kg) ^ (rb & 7);
            s16x8 af = *(const s16x8*)&Wc[(ra << 6) + (ga << 3)];
            s16x8 bf = *(const s16x8*)&Wc[(rb << 6) + (gb << 3)];
            acc = __builtin_amdgcn_mfma_f32_16x16x32_bf16(af, bf, acc, 0, 0, 0);
        }
        __syncthreads();
    }

    {
        const int di = wr * 16 + (l >> 4) * 4;
        const int dj = wc2 * 16 + (l & 15);
        #pragma unroll
        for (int r = 0; r < 4; ++r) Gs[di + r][dj] = acc[r];
    }
    for (int z = t; z < GS_N * (GS_N + 1); z += 256) ((float*)Ms)[z] = 0.f;
    __syncthreads();

    // Cholesky, lower triangle in place (diag in Ld)
    for (int k = 0; k < GS_N; ++k) {
        const float sk = sqrtf(Gs[k][k]);
        if (t == k) Ld[k] = sk;
        if (t > k && t < GS_N) Gs[t][k] /= sk;
        __syncthreads();
        if (t > k && t < GS_N) {
            const float lik = Gs[t][k];
            for (int j = k + 1; j <= t; ++j)
                Gs[t][j] -= lik * Gs[j][k];
        }
        __syncthreads();
    }

    // M = diag(L) * L^-1, column-parallel forward substitution
    if (t < GS_N) {
        const int j = t;
        Ms[j][j] = 1.0f / Ld[j];
        for (int i = j + 1; i < GS_N; ++i) {
            float a = 0.f;
            for (int k = j; k < i; ++k)
                a += Gs[i][k] * Ms[k][j];
            Ms[i][j] = -a / Ld[i];
        }
        for (int i = j + 1; i < GS_N; ++i)
            Ms[i][j] *= Ld[i];
    }
    __syncthreads();

    {
        const int i = t >> 3, j0 = (t & 7) << 2;
        float4 mv = make_float4(Ms[i][j0], Ms[i][j0 + 1],
                                Ms[i][j0 + 2], Ms[i][j0 + 3]);
        *(float4*)(Mws + (size_t)blockIdx.x * 1024 + (t << 2)) = mv;
    }
}

// ======================= K4b: apply correction =============================
__global__ __launch_bounds__(256, 8) void gs_apply(
    float* __restrict__ out, const float* __restrict__ Mws)
{
    __shared__ float4 Wf[GS_N][28];     // 14336 B (f32 chunk)
    __shared__ float  Ml[GS_N][36];     // 4608 B (padded for f4 writes)

    const int t = threadIdx.x;
    const int b = blockIdx.y;
    const int k0 = blockIdx.x * 112;
    float* row0 = out + (size_t)b * (GS_N * GS_D);

    {
        float4 mv = *(const float4*)(Mws + (size_t)b * 1024 + (t << 2));
        const int i = t >> 3, j0 = (t & 7) << 2;
        *(float4*)&Ml[i][j0] = mv;
    }
    #pragma unroll
    for (int hh = 0; hh < 4; ++hh) {
        const int h = t + hh * 256;     // 0..1023
        const int r = h >> 5, c = h & 31;
        if (c < 28)
            Wf[r][c] = *(const float4*)(row0 + r * GS_D + k0 + (c << 2));
    }
    __syncthreads();

    const int rg = t >> 5;              // row group: rows rg*4 .. rg*4+3
    const int c4 = t & 31;              // float4 column
    if (c4 < 28) {
        const int i0 = rg << 2;
        float4 c0 = Wf[i0 + 0][c4];
        float4 c1 = Wf[i0 + 1][c4];
        float4 c2 = Wf[i0 + 2][c4];
        float4 c3 = Wf[i0 + 3][c4];
        for (int j = 0; j < GS_N - 1; ++j) {
            if (j > i0 + 2) break;
            const float4 wj = Wf[j][c4];
            const float m0 = (i0 + 0 > j) ? Ml[i0 + 0][j] : 0.f;
            const float m1 = (i0 + 1 > j) ? Ml[i0 + 1][j] : 0.f;
            const float m2 = (i0 + 2 > j) ? Ml[i0 + 2][j] : 0.f;
            const float m3 = (i0 + 3 > j) ? Ml[i0 + 3][j] : 0.f;
            c0.x += m0 * wj.x; c0.y += m0 * wj.y;
            c0.z += m0 * wj.z; c0.w += m0 * wj.w;
            c1.x += m1 * wj.x; c1.y += m1 * wj.y;
            c1.z += m1 * wj.z; c1.w += m1 * wj.w;
            c2.x += m2 * wj.x; c2.y += m2 * wj.y;
            c2.z += m2 * wj.z; c2.w += m2 * wj.w;
            c3.x += m3 * wj.x; c3.y += m3 * wj.y;
            c3.z += m3 * wj.z; c3.w += m3 * wj.w;
        }
        *(float4*)(row0 + (i0 + 0) * GS_D + k0 + (c4 << 2)) = c0;
        *(float4*)(row0 + (i0 + 1) * GS_D + k0 + (c4 << 2)) = c1;
        *(float4*)(row0 + (i0 + 2) * GS_D + k0 + (c4 << 2)) = c2;
        *(float4*)(row0 + (i0 + 3) * GS_D + k0 + (c4 << 2)) = c3;
    }
}

// ================================ launch ===================================
extern "C" void kernel_launch(void* const* d_in, const int* in_sizes, int n_in,
                              void* d_out, int out_size, void* d_ws, size_t ws_size,
                              hipStream_t stream)
{
    const float* xd   = (const float*)d_in[0];  // [2048, 832]
    const float* xr   = (const float*)d_in[1];  // [2048, 1, 28, 28]
    const float* Wlp  = (const float*)d_in[2];  // [784, 832]
    const float* blp  = (const float*)d_in[3];  // [784]
    const float* Wnet = (const float*)d_in[4];  // [25088, 1568]
    const float* bnet = (const float*)d_in[5];  // [25088]
    float* out = (float*)d_out;                 // [2048, 32, 784] f32

    const int B = 2048, IN_LP = 832, IMG = 784, IN_NET = 1568, OUT = 32 * 784;

    __hip_bfloat16* Wnet_bf = (__hip_bfloat16*)d_ws;
    __hip_bfloat16* x_bf =
        (__hip_bfloat16*)((char*)d_ws + (size_t)OUT * IN_NET * 2);
    // M workspace overlays Wnet_bf region (free after K3; stream-ordered).
    float* Mws = (float*)d_ws;                  // [2048][32][32] f32 = 8.4 MB

    // K0: W_net fp32 -> bf16
    f32_to_bf16<<<2048, 256, 0, stream>>>(Wnet, Wnet_bf, OUT * IN_NET / 4);

    // K1: linear projection + normalize -> bf16 x[:, :784]
    gemm_nt_lp<<<dim3((IMG + TILE_N - 1) / TILE_N, B / TILE_M), 256, 0, stream>>>(
        xd, Wlp, blp, x_bf, B, IMG, IN_LP, IN_NET);

    // K2: normalized restored image -> bf16 x[:, 784:]
    build_restored<<<B, 256, 0, stream>>>(xr, x_bf);

    // K3: big MFMA GEMM -> d_out (fp32); grid 784 = 8 XCD bands x 98
    gemm_mfma_256<<<dim3(784), 512, 0, stream>>>(
        x_bf, Wnet_bf, bnet, out, B, OUT, IN_NET);

    // K4a: per-batch Gram + Cholesky -> M
    gram_solve<<<B, 256, 0, stream>>>(out, Mws);

    // K4b: apply rank-32 correction in place
    gs_apply<<<dim3(7, B), 256, 0, stream>>>(out, Mws);
}